// Round 9
// baseline (426.485 us; speedup 1.0000x reference)
//
#include <hip/hip_runtime.h>

// VectorQuantizer: x [32768, 256] fp32, codebook [1024, 256] fp32.
// Reference (recomputed by harness in float32):
//   d[n,k] = fl( fl( ||x_n||^2 - 2*dot(x_n,c_k) ) + ||c_k||^2 )   (all fp32)
//   idx = argmin_k (first min), out = codebook[idx]
// fp32-replica rules (unchanged since R0):
//  - dot: single sequential fp32 FMA chain over d ascending per (n,k).
//    (Here: d-slabs ascending x within-slab d ascending == same global chain.)
//  - q = (S - 2*acc) + cn: two fp32 roundings, left-to-right (computed ONCE,
//    after the full dot — identical to reference, which also rounds once).
//  - S/cnorm: fp64 butterfly sums rounded once to fp32 (norms kernel as R0).
//  - ties -> smallest k (strict <, per-thread k ascending; merges tie-break
//    on smaller index) == np.argmin first-hit.
//
// Round ledger (measured laws):
//  L1 Register ARRAYS across barriers spill at tight VGPR caps (R1-R3);
//     safe at cap 256 (launch_bounds min-waves 1; R5 104 VGPR no spill).
//  L2 Wave-uniform global VECTOR loads in the hot loop: 16 B/instr + full
//     latency exposure (R4 9.5x, R6). Scalar (SGPR) uniform loads of
//     once-read data are different and fine.
//  L3 LDS pipe demand ratio must be < 1 (b128 ~12 cy, 1 pipe/CU, 4 SIMDs).
//  L4 1 wave/SIMD = no latency hiding (R5).
//  L5/L6 LDS bank laws: lane-sweep staging; stride-260 or XOR-swizzled rows.
//  L7 (R8, new): repeated x re-reads overflow the 4 MB/XCD L2 (5 MB set) ->
//     a-loads served by L3 at ~500 cy; FETCH_SIZE stays low (L3 masks it)
//     but each inner iteration stalls ~1200 cy. TLP-insensitive (R5->R8
//     only +21% from 2x waves). Fix = remove globals from the inner loop.
// R9: LOOP INTERCHANGE. Outer loop over 32 d-slabs (8 d each):
//  - x slab -> SGPRs via readfirstlane-uniform base (read ONCE total).
//  - cb slab (1024 k x 8 d = 32 KB) staged to XOR-swizzled LDS per slab.
//  - thread (kj=tid&127, ty=tid>>7): acc[8 rows][8 ks] persists in VGPRs.
//  - per j: 2 conflict-free ds_read_b128 per 128 issue-cy -> LDS ratio 0.75,
//    ZERO global loads in the hot loop (single-counter lgkm scheduling).

#define D         256
#define K_TOTAL   1024
#define N_ROWS    32768
#define TM        32            // rows per block -> grid 1024 (4 rounds of 256)
#define NTHREADS  512           // 8 waves = 2/SIMD
#define NI        8             // rows per thread (ty = tid>>7, wave-uniform)
#define NJ        8             // ks per thread (k = kj + 128*j)
#define DSLAB     8
#define NSLAB     (D / DSLAB)   // 32

// ---------------- kernel 1: row norms for x and codebook ----------------
// Unchanged (bit-exact): fp32 squares -> fp64 left-assoc sum of 4 ->
// shfl_down butterfly 32..1 -> single fp64->fp32 rounding.
__global__ void norms_kernel(const float* __restrict__ x, const float* __restrict__ cb,
                             float* __restrict__ xnorm, float* __restrict__ cnorm) {
    const int wave = threadIdx.x >> 6;          // 0..3
    const int lane = threadIdx.x & 63;
    const int row0 = (blockIdx.x * 4 + wave) * 4;   // 4 rows per wave

    double s[4];
    #pragma unroll
    for (int r = 0; r < 4; ++r) {
        const int row = row0 + r;
        const float* src = (row < N_ROWS) ? (x + (size_t)row * D)
                                          : (cb + (size_t)(row - N_ROWS) * D);
        float4 v = *(const float4*)(src + lane * 4);
        float sx = v.x * v.x;
        float sy = v.y * v.y;
        float sz = v.z * v.z;
        float sw = v.w * v.w;
        s[r] = (double)sx + (double)sy + (double)sz + (double)sw;
    }
    #pragma unroll
    for (int off = 32; off > 0; off >>= 1) {
        #pragma unroll
        for (int r = 0; r < 4; ++r) s[r] += __shfl_down(s[r], off, 64);
    }
    if (lane == 0) {
        #pragma unroll
        for (int r = 0; r < 4; ++r) {
            const int row = row0 + r;
            if (row < N_ROWS) xnorm[row] = (float)s[r];
            else              cnorm[row - N_ROWS] = (float)s[r];
        }
    }
}

// XOR-swizzled word index into the cb slab: row k = 8 floats (32 B).
// word = 8k+f, swizzled by ((k&7)<<2): preserves low 2 bits (16B-aligned
// float4 stays contiguous) and spreads 8 consecutive rows across all 32
// banks -> conflict-free b128 for both staging writes (k=tid) and reads
// (k=kj consecutive). Verified by construction: start banks for k&7 =
// {0,12,24,20,16,28,8,4}, each b128 covers start..start+3 -> full coverage.
__device__ __forceinline__ int cs_word(int k, int f) {
    return ((k << 3) + f) ^ ((k & 7) << 2);
}

// ---------------- kernel 2: d-slab interchange, x in scalar regs ----------------
__global__ __launch_bounds__(NTHREADS, 1)   // cap 256 VGPR: no allocator squeeze
void vq_kernel(const float* __restrict__ x, const float* __restrict__ cb,
               const float* __restrict__ xnorm, const float* __restrict__ cnorm,
               float* __restrict__ out) {
    __shared__ float cs[K_TOTAL * DSLAB];    // 32768 B swizzled cb slab
    __shared__ float bv2[TM * 2];            // per-row, per-kj-half candidates
    __shared__ int   bi2[TM * 2];
    __shared__ int   best[TM];

    const int tid = threadIdx.x;
    const int kj  = tid & 127;               // k-owner: k = kj + 128*j
    const int ty  = __builtin_amdgcn_readfirstlane(tid >> 7);  // 0..3, uniform
    const int n0  = blockIdx.x * TM;

    const float* xw = x + (size_t)(n0 + ty * NI) * D;   // uniform base -> s_load

    // wave-uniform row norms -> scalar regs
    float S[NI];
    #pragma unroll
    for (int r = 0; r < NI; ++r) S[r] = xnorm[n0 + ty * NI + r];

    // per-thread codebook norms (read once)
    float cn[NJ];
    #pragma unroll
    for (int j = 0; j < NJ; ++j) cn[j] = cnorm[kj + 128 * j];

    float acc[NI][NJ];
    #pragma unroll
    for (int r = 0; r < NI; ++r)
        #pragma unroll
        for (int j = 0; j < NJ; ++j) acc[r][j] = 0.f;

    #pragma unroll 1
    for (int s = 0; s < NSLAB; ++s) {
        const int dd = s * DSLAB;

        // x slab -> (scalar) regs; uniform addresses, issued before the
        // barrier so they complete under the staging.
        float xs[NI][DSLAB];
        #pragma unroll
        for (int r = 0; r < NI; ++r) {
            const float4 u0 = *(const float4*)(xw + r * D + dd);
            const float4 u1 = *(const float4*)(xw + r * D + dd + 4);
            xs[r][0] = u0.x; xs[r][1] = u0.y; xs[r][2] = u0.z; xs[r][3] = u0.w;
            xs[r][4] = u1.x; xs[r][5] = u1.y; xs[r][6] = u1.z; xs[r][7] = u1.w;
        }

        __syncthreads();                     // previous slab's readers done
        {   // stage cb slab: rows tid and tid+512, 32 B each, swizzled LDS.
            #pragma unroll
            for (int h = 0; h < 2; ++h) {
                const int k = tid + 512 * h;
                const float4 u0 = *(const float4*)(cb + (size_t)k * D + dd);
                const float4 u1 = *(const float4*)(cb + (size_t)k * D + dd + 4);
                *(float4*)(cs + cs_word(k, 0)) = u0;
                *(float4*)(cs + cs_word(k, 4)) = u1;
            }
        }
        __syncthreads();

        // hot loop: per j, 2 conflict-free ds_read_b128 + 64 FMA (128 cy).
        // Sequential fp32 chain per (row,k): d ascending — DO NOT reorder.
        #pragma unroll
        for (int j = 0; j < NJ; ++j) {
            const int k = kj + 128 * j;
            const float4 b0 = *(const float4*)(cs + cs_word(k, 0));
            const float4 b1 = *(const float4*)(cs + cs_word(k, 4));
            const float bb[DSLAB] = {b0.x, b0.y, b0.z, b0.w,
                                     b1.x, b1.y, b1.z, b1.w};
            #pragma unroll
            for (int r = 0; r < NI; ++r)
                #pragma unroll
                for (int d = 0; d < DSLAB; ++d)
                    acc[r][j] += xs[r][d] * bb[d];
        }
    }

    // ---- epilogue: np-replica distance (two roundings), per-thread scan ----
    float runmin[NI];
    int   runidx[NI];
    #pragma unroll
    for (int r = 0; r < NI; ++r) { runmin[r] = 1e30f; runidx[r] = 0; }
    #pragma unroll
    for (int j = 0; j < NJ; ++j) {           // j ascending == k ascending
        const int k = kj + 128 * j;
        #pragma unroll
        for (int r = 0; r < NI; ++r) {
            const float t = S[r] - 2.0f * acc[r][j];   // one rounding (2*acc exact)
            const float q = t + cn[j];                 // second rounding
            if (q < runmin[r]) { runmin[r] = q; runidx[r] = k; }
        }
    }

    // ---- 64-lane butterfly per row (disjoint k per lane), index tie-break ----
    const int lane = tid & 63;
    const int half = (tid >> 6) & 1;         // kj-half of this wave
    #pragma unroll
    for (int r = 0; r < NI; ++r) {
        float v = runmin[r];
        int  ix = runidx[r];
        #pragma unroll
        for (int off = 32; off > 0; off >>= 1) {
            const float ov = __shfl_xor(v, off, 64);
            const int   oi = __shfl_xor(ix, off, 64);
            if (ov < v || (ov == v && oi < ix)) { v = ov; ix = oi; }
        }
        if (lane == 0) {
            const int row = ty * NI + r;
            bv2[row * 2 + half] = v;
            bi2[row * 2 + half] = ix;
        }
    }
    __syncthreads();
    if (tid < TM) {
        const float v0 = bv2[tid * 2];
        const int   i0 = bi2[tid * 2];
        const float v1 = bv2[tid * 2 + 1];
        const int   i1 = bi2[tid * 2 + 1];
        best[tid] = (v1 < v0 || (v1 == v0 && i1 < i0)) ? i1 : i0;
    }
    __syncthreads();

    // ---- gather winning codebook rows -> out, coalesced 16B ----
    {
        const int grow = tid >> 4;           // 0..31
        const int gc4  = tid & 15;           // 0..15
        const int kk   = best[grow];
        #pragma unroll
        for (int p = 0; p < 4; ++p) {
            const float4 v = *(const float4*)(cb + (size_t)kk * D + (gc4 + 16 * p) * 4);
            *(float4*)(out + (size_t)(n0 + grow) * D + (gc4 + 16 * p) * 4) = v;
        }
    }
}

extern "C" void kernel_launch(void* const* d_in, const int* in_sizes, int n_in,
                              void* d_out, int out_size, void* d_ws, size_t ws_size,
                              hipStream_t stream) {
    const float* x  = (const float*)d_in[0];   // [32768, 256]
    const float* cb = (const float*)d_in[1];   // [1024, 256]
    float* out = (float*)d_out;                // [32768, 256]

    // workspace: xnorm [32768 fp32] | cnorm [1024 fp32]  (132 KB)
    float* xnorm = (float*)d_ws;
    float* cnorm = xnorm + N_ROWS;

    norms_kernel<<<(N_ROWS + K_TOTAL) / 16, 256, 0, stream>>>(x, cb, xnorm, cnorm);
    vq_kernel<<<N_ROWS / TM, NTHREADS, 0, stream>>>(x, cb, xnorm, cnorm, out);
}